// Round 1
// baseline (136.478 us; speedup 1.0000x reference)
//
#include <hip/hip_runtime.h>

// LVAE_shGLM encoder, fused bf16-MFMA implementation for gfx950.
//
//   h_mid  = relu(windows @ W1 + b1)   windows[t,k] = pad[t+k], pad = 99 zeros | V | 99 zeros
//   mu_mid = h_mid @ W2 + b2           -> out[:, 0:4]
//   h_leaf = relu(h_mid @ Wl1 + bl1)
//   mu_leaf= h_leaf @ Wl2 + bl2        -> out[:, 4:20]
//
// ws usage: 262144 bytes of packed bf16 weight fragments.

typedef __bf16 bf16;
typedef __bf16 bf16x8 __attribute__((ext_vector_type(8)));
typedef float  f32x4  __attribute__((ext_vector_type(4)));

constexpr int T_DATA = 100000;
constexpr int T_V    = 100;
constexpr int WIN    = 199;   // 2*T_V - 1
constexpr int HID    = 256;
constexpr int BT     = 128;   // timesteps per block
constexpr int RPW    = 32;    // rows per wave (2 MFMA row-tiles)
constexpr int KT1    = 7;     // GEMM1 k-tiles: K padded 199 -> 224
constexpr int KT2    = 8;     // 256 / 32

// ws layout in bf16 elements. Each "group" = 64 lanes * 8 bf16 = 512 elems = one
// B fragment set for a 32(K) x 16(N) weight tile, lane-major so the main loop
// loads one coalesced 16B chunk per lane.
constexpr int PW1_OFF  = 0;               // 112 groups (7 kt * 16 nt)
constexpr int PWL1_OFF = 112 * 512;       // 128 groups (8 kt * 16 nt)
constexpr int PW2_OFF  = PWL1_OFF + 128 * 512;  // 8 groups (8 kt, 4 real cols)
constexpr int PWL2_OFF = PW2_OFF + 8 * 512;     // 8 groups (8 kt, 16 cols)
// total = 256 groups * 512 * 2B = 262144 bytes

__global__ void pack_weights(const float* __restrict__ W1, const float* __restrict__ W2,
                             const float* __restrict__ Wl1, const float* __restrict__ Wl2,
                             bf16* __restrict__ ws) {
  const int gid  = blockIdx.x * blockDim.x + threadIdx.x;  // [0, 16384)
  const int lane = gid & 63;
  const int grp  = gid >> 6;        // [0, 256)
  const int m    = lane & 15;       // fragment col (N)
  const int g    = lane >> 4;       // k-group
  bf16x8 v;
  if (grp < 112) {                  // PW1: grp = kt*16 + nt
    const int kt = grp >> 4, nt = grp & 15, n = nt * 16 + m;
#pragma unroll
    for (int j = 0; j < 8; ++j) {
      const int k = kt * 32 + g * 8 + j;
      v[j] = (k < WIN) ? (bf16)W1[k * HID + n] : (bf16)0.0f;
    }
  } else if (grp < 240) {           // PWl1
    const int q = grp - 112;
    const int kt = q >> 4, nt = q & 15, n = nt * 16 + m;
#pragma unroll
    for (int j = 0; j < 8; ++j) {
      const int k = kt * 32 + g * 8 + j;
      v[j] = (bf16)Wl1[k * HID + n];
    }
  } else if (grp < 248) {           // PW2: only cols 0..3 real, rest zero
    const int kt = grp - 240;
#pragma unroll
    for (int j = 0; j < 8; ++j) {
      const int k = kt * 32 + g * 8 + j;
      v[j] = (m < 4) ? (bf16)W2[k * 4 + m] : (bf16)0.0f;
    }
  } else {                          // PWl2: 16 cols
    const int kt = grp - 248;
#pragma unroll
    for (int j = 0; j < 8; ++j) {
      const int k = kt * 32 + g * 8 + j;
      v[j] = (bf16)Wl2[k * 16 + m];
    }
  }
  *reinterpret_cast<bf16x8*>(ws + (size_t)gid * 8) = v;
}

__global__ __launch_bounds__(256, 2) void fused_enc(
    const float* __restrict__ V, const float* __restrict__ b1,
    const float* __restrict__ b2, const float* __restrict__ bl1,
    const float* __restrict__ bl2, const bf16* __restrict__ ws,
    float* __restrict__ out) {
  __shared__ float Vs[BT + 224];        // window slice (fp32 so ds_read_b32 stays aligned)
  __shared__ bf16  hbuf[BT * HID];      // 64 KB, XOR-swizzled; per-wave row regions

  const int tid  = threadIdx.x;
  const int lane = tid & 63;
  const int w    = tid >> 6;
  const int m    = lane & 15;           // A-frag row / C col
  const int g    = lane >> 4;           // k-group / C row-group
  const long t0  = (long)blockIdx.x * BT;

  // Stage padded window slice: Vs[i] = pad[t0 + i], pad[p] = V[p - 99] (0 outside)
  for (int i = tid; i < BT + 224; i += 256) {
    const long src = t0 - (T_V - 1) + i;
    Vs[i] = (src >= 0 && src < T_DATA) ? V[src] : 0.0f;
  }
  __syncthreads();  // only barrier: everything below is wave-private

  const bf16* PW1  = ws + PW1_OFF;
  const bf16* PWl1 = ws + PWL1_OFF;
  const bf16* PW2  = ws + PW2_OFF;
  const bf16* PWl2 = ws + PWL2_OFF;

  const int r0   = w * RPW;             // wave's first local row
  const int ar0  = r0 + m;              // A row, row-tile 0
  const int ar1  = r0 + 16 + m;         // A row, row-tile 1
  const int swz0 = (ar0 & 7) << 3;
  const int swz1 = (ar1 & 7) << 3;

  f32x4 acc[2][16];
#pragma unroll
  for (int rt = 0; rt < 2; ++rt)
#pragma unroll
    for (int ct = 0; ct < 16; ++ct) acc[rt][ct] = (f32x4){0.f, 0.f, 0.f, 0.f};

  // ---------- GEMM1: h_mid(pre-act) = windows @ W1 ----------
#pragma unroll
  for (int kt = 0; kt < KT1; ++kt) {
    const int kb = kt * 32 + g * 8;
    bf16x8 a0, a1;
#pragma unroll
    for (int j = 0; j < 8; ++j) {
      a0[j] = (bf16)Vs[ar0 + kb + j];
      a1[j] = (bf16)Vs[ar1 + kb + j];
    }
    const bf16x8* bp = reinterpret_cast<const bf16x8*>(PW1 + (size_t)(kt * 16) * 512 + lane * 8);
#pragma unroll
    for (int ct = 0; ct < 16; ++ct) {
      const bf16x8 b = bp[ct * 64];
      acc[0][ct] = __builtin_amdgcn_mfma_f32_16x16x32_bf16(a0, b, acc[0][ct], 0, 0, 0);
      acc[1][ct] = __builtin_amdgcn_mfma_f32_16x16x32_bf16(a1, b, acc[1][ct], 0, 0, 0);
    }
  }

  // bias + relu + store h_mid to LDS (swizzled: c ^ ((r&7)<<3) keeps b128 reads conflict-light)
#pragma unroll
  for (int ct = 0; ct < 16; ++ct) {
    const float bb = b1[ct * 16 + m];
#pragma unroll
    for (int rt = 0; rt < 2; ++rt) {
#pragma unroll
      for (int j = 0; j < 4; ++j) {
        const int r = r0 + rt * 16 + g * 4 + j;
        float h = acc[rt][ct][j] + bb;
        h = fmaxf(h, 0.0f);
        const int c = ct * 16 + m;
        hbuf[r * HID + (c ^ ((r & 7) << 3))] = (bf16)h;
      }
    }
  }

#pragma unroll
  for (int rt = 0; rt < 2; ++rt)
#pragma unroll
    for (int ct = 0; ct < 16; ++ct) acc[rt][ct] = (f32x4){0.f, 0.f, 0.f, 0.f};

  f32x4 mu2[2] = {(f32x4){0.f, 0.f, 0.f, 0.f}, (f32x4){0.f, 0.f, 0.f, 0.f}};

  // ---------- GEMM3: h_leaf(pre-act) = h_mid @ Wl1, fused GEMM2: mu_mid = h_mid @ W2 ----------
#pragma unroll
  for (int kt = 0; kt < KT2; ++kt) {
    const int kb = kt * 32 + g * 8;
    const bf16x8 a0 = *reinterpret_cast<const bf16x8*>(&hbuf[ar0 * HID + (kb ^ swz0)]);
    const bf16x8 a1 = *reinterpret_cast<const bf16x8*>(&hbuf[ar1 * HID + (kb ^ swz1)]);
    const bf16x8* bp = reinterpret_cast<const bf16x8*>(PWl1 + (size_t)(kt * 16) * 512 + lane * 8);
#pragma unroll
    for (int ct = 0; ct < 16; ++ct) {
      const bf16x8 b = bp[ct * 64];
      acc[0][ct] = __builtin_amdgcn_mfma_f32_16x16x32_bf16(a0, b, acc[0][ct], 0, 0, 0);
      acc[1][ct] = __builtin_amdgcn_mfma_f32_16x16x32_bf16(a1, b, acc[1][ct], 0, 0, 0);
    }
    const bf16x8 bw2 = *reinterpret_cast<const bf16x8*>(PW2 + (size_t)kt * 512 + lane * 8);
    mu2[0] = __builtin_amdgcn_mfma_f32_16x16x32_bf16(a0, bw2, mu2[0], 0, 0, 0);
    mu2[1] = __builtin_amdgcn_mfma_f32_16x16x32_bf16(a1, bw2, mu2[1], 0, 0, 0);
  }

  // bias + relu + store h_leaf (overwrites this wave's own rows; in-wave LDS ordering is safe)
#pragma unroll
  for (int ct = 0; ct < 16; ++ct) {
    const float bb = bl1[ct * 16 + m];
#pragma unroll
    for (int rt = 0; rt < 2; ++rt) {
#pragma unroll
      for (int j = 0; j < 4; ++j) {
        const int r = r0 + rt * 16 + g * 4 + j;
        float h = acc[rt][ct][j] + bb;
        h = fmaxf(h, 0.0f);
        const int c = ct * 16 + m;
        hbuf[r * HID + (c ^ ((r & 7) << 3))] = (bf16)h;
      }
    }
  }

  // ---------- GEMM4: mu_leaf = h_leaf @ Wl2 ----------
  f32x4 mu4[2] = {(f32x4){0.f, 0.f, 0.f, 0.f}, (f32x4){0.f, 0.f, 0.f, 0.f}};
#pragma unroll
  for (int kt = 0; kt < KT2; ++kt) {
    const int kb = kt * 32 + g * 8;
    const bf16x8 a0 = *reinterpret_cast<const bf16x8*>(&hbuf[ar0 * HID + (kb ^ swz0)]);
    const bf16x8 a1 = *reinterpret_cast<const bf16x8*>(&hbuf[ar1 * HID + (kb ^ swz1)]);
    const bf16x8 b  = *reinterpret_cast<const bf16x8*>(PWl2 + (size_t)kt * 512 + lane * 8);
    mu4[0] = __builtin_amdgcn_mfma_f32_16x16x32_bf16(a0, b, mu4[0], 0, 0, 0);
    mu4[1] = __builtin_amdgcn_mfma_f32_16x16x32_bf16(a1, b, mu4[1], 0, 0, 0);
  }

  // ---------- epilogue: out[t, 0:4] = mu_mid, out[t, 4:20] = mu_leaf ----------
  const float bl2v = bl2[m];
  const float b2v  = (m < 4) ? b2[m] : 0.0f;
#pragma unroll
  for (int rt = 0; rt < 2; ++rt) {
#pragma unroll
    for (int j = 0; j < 4; ++j) {
      const long t = t0 + r0 + rt * 16 + g * 4 + j;   // C layout: row=(lane>>4)*4+reg, col=lane&15
      if (t < T_DATA) {
        out[t * 20 + 4 + m] = mu4[rt][j] + bl2v;
        if (m < 4) out[t * 20 + m] = mu2[rt][j] + b2v;
      }
    }
  }
}

extern "C" void kernel_launch(void* const* d_in, const int* in_sizes, int n_in,
                              void* d_out, int out_size, void* d_ws, size_t ws_size,
                              hipStream_t stream) {
  const float* V   = (const float*)d_in[0];
  const float* W1  = (const float*)d_in[1];
  const float* b1  = (const float*)d_in[2];
  const float* W2  = (const float*)d_in[3];
  const float* b2  = (const float*)d_in[4];
  const float* Wl1 = (const float*)d_in[5];
  const float* bl1 = (const float*)d_in[6];
  const float* Wl2 = (const float*)d_in[7];
  const float* bl2 = (const float*)d_in[8];
  bf16* ws = (bf16*)d_ws;   // needs 262144 bytes
  float* out = (float*)d_out;

  pack_weights<<<64, 256, 0, stream>>>(W1, W2, Wl1, Wl2, ws);

  const int grid = (T_DATA + BT - 1) / BT;   // 782
  fused_enc<<<grid, 256, 0, stream>>>(V, b1, b2, bl1, bl2, ws, out);
}

// Round 2
// 78.008 us; speedup vs baseline: 1.7495x; 1.7495x over previous
//
#include <hip/hip_runtime.h>

// LVAE_shGLM encoder, fused bf16-MFMA implementation for gfx950.
// Round 2: weight B-fragments staged per-block into double-buffered LDS via
// global_load_lds (2-phase pipeline) to kill L2/HBM-miss latency on B loads.
//
//   h_mid  = relu(windows @ W1 + b1)   windows[t,k] = pad[t+k]
//   mu_mid = h_mid @ W2 + b2           -> out[:, 0:4]
//   h_leaf = relu(h_mid @ Wl1 + bl1)
//   mu_leaf= h_leaf @ Wl2 + bl2        -> out[:, 4:20]

typedef __bf16 bf16;
typedef __bf16 bf16x8 __attribute__((ext_vector_type(8)));
typedef float  f32x4  __attribute__((ext_vector_type(4)));

constexpr int T_DATA = 100000;
constexpr int T_V    = 100;
constexpr int WIN    = 199;   // 2*T_V - 1
constexpr int HID    = 256;
constexpr int BT     = 128;   // timesteps per block
constexpr int RPW    = 32;    // rows per wave (2 MFMA row-tiles)
constexpr int NKT    = 15;    // 7 (W1, K padded 199->224) + 8 (Wl1, K=256)

// ws layout in bf16 elements (written by pack_weights):
//   [0      .. 57343 ] PW1   7 kt-tiles x 16 ct x 512   (= kt-tile stride 8192)
//   [57344  ..188415 ] PWl1  8 kt-tiles x 16 ct x 512   (contiguous with PW1)
//   [122880 ..126975 ] PW2   8 kt x 512
//   [126976 ..131071 ] PWl2  8 kt x 512
constexpr int PW1_OFF   = 0;
constexpr int PWL1_OFF  = 112 * 512;        // 57344
constexpr int PW2_OFF   = PWL1_OFF + 128 * 512;
constexpr int PWL2_OFF  = PW2_OFF + 8 * 512;
constexpr int SMALL_OFF = PW2_OFF;          // PW2||PWl2, 8192 elems = 16 KB

__global__ void pack_weights(const float* __restrict__ W1, const float* __restrict__ W2,
                             const float* __restrict__ Wl1, const float* __restrict__ Wl2,
                             bf16* __restrict__ ws) {
  const int gid  = blockIdx.x * blockDim.x + threadIdx.x;  // [0, 16384)
  const int lane = gid & 63;
  const int grp  = gid >> 6;        // [0, 256)
  const int m    = lane & 15;       // fragment col (N)
  const int g    = lane >> 4;       // k-group
  bf16x8 v;
  if (grp < 112) {                  // PW1: grp = kt*16 + nt
    const int kt = grp >> 4, nt = grp & 15, n = nt * 16 + m;
#pragma unroll
    for (int j = 0; j < 8; ++j) {
      const int k = kt * 32 + g * 8 + j;
      v[j] = (k < WIN) ? (bf16)W1[k * HID + n] : (bf16)0.0f;
    }
  } else if (grp < 240) {           // PWl1
    const int q = grp - 112;
    const int kt = q >> 4, nt = q & 15, n = nt * 16 + m;
#pragma unroll
    for (int j = 0; j < 8; ++j) {
      const int k = kt * 32 + g * 8 + j;
      v[j] = (bf16)Wl1[k * HID + n];
    }
  } else if (grp < 248) {           // PW2: only cols 0..3 real, rest zero
    const int kt = grp - 240;
#pragma unroll
    for (int j = 0; j < 8; ++j) {
      const int k = kt * 32 + g * 8 + j;
      v[j] = (m < 4) ? (bf16)W2[k * 4 + m] : (bf16)0.0f;
    }
  } else {                          // PWl2: 16 cols
    const int kt = grp - 248;
#pragma unroll
    for (int j = 0; j < 8; ++j) {
      const int k = kt * 32 + g * 8 + j;
      v[j] = (bf16)Wl2[k * 16 + m];
    }
  }
  *reinterpret_cast<bf16x8*>(ws + (size_t)gid * 8) = v;
}

// Stage one 16 KB chunk (8192 bf16) global -> LDS. 4 global_load_lds_dwordx4
// per wave; LDS dest is wave-uniform base (HW adds lane*16), global src is
// per-lane. Linear both sides.
__device__ __forceinline__ void stage16k(const bf16* __restrict__ g, bf16* l,
                                         int w, int lane) {
#pragma unroll
  for (int i = 0; i < 4; ++i) {
    const int off = (w * 4 + i) * 512;   // bf16 elems; 1024 B per wave-instr
    __builtin_amdgcn_global_load_lds(
        (const __attribute__((address_space(1))) void*)(g + off + lane * 8),
        (__attribute__((address_space(3))) void*)(l + off), 16, 0, 0);
  }
}

__global__ __launch_bounds__(256, 1) void fused_enc(
    const float* __restrict__ V, const float* __restrict__ b1,
    const float* __restrict__ b2, const float* __restrict__ bl1,
    const float* __restrict__ bl2, const bf16* __restrict__ ws,
    float* __restrict__ out) {
  __shared__ float Vs[BT + 224];        // 1408 B, fp32 window slice
  __shared__ bf16  hbuf[BT * HID];      // 64 KB, XOR-swizzled, wave-private rows
  __shared__ bf16  bsm[2][16 * 512];    // 32 KB double-buffered B kt-tile
  __shared__ bf16  bsmall[2 * 8 * 512]; // 16 KB: PW2 || PWl2

  const int tid  = threadIdx.x;
  const int lane = tid & 63;
  const int w    = tid >> 6;
  const int m    = lane & 15;           // A-frag row / C col
  const int g    = lane >> 4;           // k-group / C row-group
  const long t0  = (long)blockIdx.x * BT;

  // ---- prologue: stage tile 0 + small weights, fill Vs ----
  stage16k(ws, bsm[0], w, lane);
  stage16k(ws + SMALL_OFF, bsmall, w, lane);
  for (int i = tid; i < BT + 224; i += 256) {
    const long src = t0 - (T_V - 1) + i;
    Vs[i] = (src >= 0 && src < T_DATA) ? V[src] : 0.0f;
  }
  __syncthreads();   // drains vmcnt: bsm[0] + bsmall resident

  const int r0   = w * RPW;
  const int ar0  = r0 + m;
  const int ar1  = r0 + 16 + m;
  const int swz0 = (ar0 & 7) << 3;
  const int swz1 = (ar1 & 7) << 3;

  f32x4 acc[2][16];
#pragma unroll
  for (int rt = 0; rt < 2; ++rt)
#pragma unroll
    for (int ct = 0; ct < 16; ++ct) acc[rt][ct] = (f32x4){0.f, 0.f, 0.f, 0.f};
  f32x4 mu2[2] = {(f32x4){0.f, 0.f, 0.f, 0.f}, (f32x4){0.f, 0.f, 0.f, 0.f}};

  // ---- main K pipeline: kt 0..6 = GEMM1 (A from Vs), kt 7..14 = GEMM3(+GEMM2) ----
#pragma unroll
  for (int kt = 0; kt < NKT; ++kt) {
    const int cur = kt & 1;
    if (kt + 1 < NKT)                       // prefetch next kt-tile into other buffer
      stage16k(ws + (size_t)(kt + 1) * 8192, bsm[cur ^ 1], w, lane);

    bf16x8 a0, a1;
    if (kt < 7) {                           // A from sliding window (fp32 -> bf16)
      const int kb = kt * 32 + g * 8;
#pragma unroll
      for (int j = 0; j < 8; ++j) {
        a0[j] = (bf16)Vs[ar0 + kb + j];
        a1[j] = (bf16)Vs[ar1 + kb + j];
      }
    } else {                                // A from swizzled h_mid in LDS
      const int kb = (kt - 7) * 32 + g * 8;
      a0 = *reinterpret_cast<const bf16x8*>(&hbuf[ar0 * HID + (kb ^ swz0)]);
      a1 = *reinterpret_cast<const bf16x8*>(&hbuf[ar1 * HID + (kb ^ swz1)]);
    }

    const bf16* bp = bsm[cur] + lane * 8;
#pragma unroll
    for (int ct = 0; ct < 16; ++ct) {
      const bf16x8 b = *reinterpret_cast<const bf16x8*>(bp + ct * 512);
      acc[0][ct] = __builtin_amdgcn_mfma_f32_16x16x32_bf16(a0, b, acc[0][ct], 0, 0, 0);
      acc[1][ct] = __builtin_amdgcn_mfma_f32_16x16x32_bf16(a1, b, acc[1][ct], 0, 0, 0);
    }

    if (kt >= 7) {                          // fused GEMM2: mu_mid = h_mid @ W2
      const bf16x8 bw2 = *reinterpret_cast<const bf16x8*>(bsmall + (kt - 7) * 512 + lane * 8);
      mu2[0] = __builtin_amdgcn_mfma_f32_16x16x32_bf16(a0, bw2, mu2[0], 0, 0, 0);
      mu2[1] = __builtin_amdgcn_mfma_f32_16x16x32_bf16(a1, bw2, mu2[1], 0, 0, 0);
    }

    if (kt == 6) {
      // h_mid epilogue: bias+relu, store to own hbuf rows (swizzled), reset acc
#pragma unroll
      for (int ct = 0; ct < 16; ++ct) {
        const float bb = b1[ct * 16 + m];
#pragma unroll
        for (int rt = 0; rt < 2; ++rt) {
#pragma unroll
          for (int j = 0; j < 4; ++j) {
            const int r = r0 + rt * 16 + g * 4 + j;
            float h = fmaxf(acc[rt][ct][j] + bb, 0.0f);
            const int c = ct * 16 + m;
            hbuf[r * HID + (c ^ ((r & 7) << 3))] = (bf16)h;
            acc[rt][ct][j] = 0.0f;
          }
        }
      }
    }
    __syncthreads();   // drains vmcnt (prefetch landed) + all waves done with bsm[cur]
  }

  // ---- h_leaf epilogue: bias+relu, overwrite own hbuf rows ----
#pragma unroll
  for (int ct = 0; ct < 16; ++ct) {
    const float bb = bl1[ct * 16 + m];
#pragma unroll
    for (int rt = 0; rt < 2; ++rt) {
#pragma unroll
      for (int j = 0; j < 4; ++j) {
        const int r = r0 + rt * 16 + g * 4 + j;
        float h = fmaxf(acc[rt][ct][j] + bb, 0.0f);
        const int c = ct * 16 + m;
        hbuf[r * HID + (c ^ ((r & 7) << 3))] = (bf16)h;
      }
    }
  }

  // ---- GEMM4: mu_leaf = h_leaf @ Wl2 (B frags from bsmall upper half) ----
  f32x4 mu4[2] = {(f32x4){0.f, 0.f, 0.f, 0.f}, (f32x4){0.f, 0.f, 0.f, 0.f}};
#pragma unroll
  for (int kq = 0; kq < 8; ++kq) {
    const int kb = kq * 32 + g * 8;
    const bf16x8 a0 = *reinterpret_cast<const bf16x8*>(&hbuf[ar0 * HID + (kb ^ swz0)]);
    const bf16x8 a1 = *reinterpret_cast<const bf16x8*>(&hbuf[ar1 * HID + (kb ^ swz1)]);
    const bf16x8 b  = *reinterpret_cast<const bf16x8*>(bsmall + 4096 + kq * 512 + lane * 8);
    mu4[0] = __builtin_amdgcn_mfma_f32_16x16x32_bf16(a0, b, mu4[0], 0, 0, 0);
    mu4[1] = __builtin_amdgcn_mfma_f32_16x16x32_bf16(a1, b, mu4[1], 0, 0, 0);
  }

  // ---- epilogue: out[t, 0:4] = mu_mid, out[t, 4:20] = mu_leaf ----
  const float bl2v = bl2[m];
  const float b2v  = (m < 4) ? b2[m] : 0.0f;
#pragma unroll
  for (int rt = 0; rt < 2; ++rt) {
#pragma unroll
    for (int j = 0; j < 4; ++j) {
      const long t = t0 + r0 + rt * 16 + g * 4 + j;  // C layout: row=(lane>>4)*4+reg, col=lane&15
      if (t < T_DATA) {
        out[t * 20 + 4 + m] = mu4[rt][j] + bl2v;
        if (m < 4) out[t * 20 + m] = mu2[rt][j] + b2v;
      }
    }
  }
}

extern "C" void kernel_launch(void* const* d_in, const int* in_sizes, int n_in,
                              void* d_out, int out_size, void* d_ws, size_t ws_size,
                              hipStream_t stream) {
  const float* V   = (const float*)d_in[0];
  const float* W1  = (const float*)d_in[1];
  const float* b1  = (const float*)d_in[2];
  const float* W2  = (const float*)d_in[3];
  const float* b2  = (const float*)d_in[4];
  const float* Wl1 = (const float*)d_in[5];
  const float* bl1 = (const float*)d_in[6];
  const float* Wl2 = (const float*)d_in[7];
  const float* bl2 = (const float*)d_in[8];
  bf16* ws = (bf16*)d_ws;   // needs 262144 bytes
  float* out = (float*)d_out;

  pack_weights<<<64, 256, 0, stream>>>(W1, W2, Wl1, Wl2, ws);

  const int grid = (T_DATA + BT - 1) / BT;   // 782
  fused_enc<<<grid, 256, 0, stream>>>(V, b1, b2, bl1, bl2, ws, out);
}